// Round 1
// baseline (281.534 us; speedup 1.0000x reference)
//
#include <hip/hip_runtime.h>
#include <cstdint>

#define NN 4096
#define FIN 512
#define DD 64
#define HH 8
#define CC 16
#define KHOP 2
#define ALPHA 0.2f
#define BETA 0.9f

typedef __attribute__((ext_vector_type(8))) short short8;
typedef __attribute__((ext_vector_type(4))) float floatx4;

static __device__ __forceinline__ uint16_t f2bf(float f) {  // RTNE
    uint32_t u = __float_as_uint(f);
    u += 0x7FFFu + ((u >> 16) & 1u);
    return (uint16_t)(u >> 16);
}

// nonzero-byte nibble: bit i set iff byte i of x is nonzero
static __device__ __forceinline__ uint32_t nz_nib(uint32_t x) {
    uint32_t zero80 = (x - 0x01010101u) & ~x & 0x80808080u;  // 0x80 where byte==0
    uint32_t nz80 = zero80 ^ 0x80808080u;                    // 0x80 where byte!=0
    return ((nz80 >> 7) * 0x01020408u) >> 24;                // bits 0..3
}

// ---- fused prep: bitmask (0..1023) + W transpose (1024..1087) + x->bf16 (1088..1599) ----
__global__ __launch_bounds__(256) void bits_prep(const uint32_t* __restrict__ mraw,
                                                 uint64_t* __restrict__ bits,
                                                 const float* __restrict__ W,
                                                 uint16_t* __restrict__ Wt,
                                                 const float* __restrict__ x,
                                                 uint16_t* __restrict__ xb) {
    const int tid = threadIdx.x;
    if (blockIdx.x >= 1088) {  // ---- xb[i] = bf16(x[i]), 16 elems/thread ----
        const int b = blockIdx.x - 1088;
        const size_t base = ((size_t)b * 256 + tid) * 16;
        float4 v0 = *(const float4*)&x[base];
        float4 v1 = *(const float4*)&x[base + 4];
        float4 v2 = *(const float4*)&x[base + 8];
        float4 v3 = *(const float4*)&x[base + 12];
        uint4 o0, o1;
        o0.x = f2bf(v0.x) | ((uint32_t)f2bf(v0.y) << 16);
        o0.y = f2bf(v0.z) | ((uint32_t)f2bf(v0.w) << 16);
        o0.z = f2bf(v1.x) | ((uint32_t)f2bf(v1.y) << 16);
        o0.w = f2bf(v1.z) | ((uint32_t)f2bf(v1.w) << 16);
        o1.x = f2bf(v2.x) | ((uint32_t)f2bf(v2.y) << 16);
        o1.y = f2bf(v2.z) | ((uint32_t)f2bf(v2.w) << 16);
        o1.z = f2bf(v3.x) | ((uint32_t)f2bf(v3.y) << 16);
        o1.w = f2bf(v3.z) | ((uint32_t)f2bf(v3.w) << 16);
        *(uint4*)&xb[base] = o0;
        *(uint4*)&xb[base + 8] = o1;
        return;
    }
    if (blockIdx.x >= 1024) {  // ---- prep: Wt[h][d][k] = bf16(W[h][k][d]) ----
        const int b = blockIdx.x - 1024;
        const int h = b >> 3, kt = b & 7;
        __shared__ float tile[64][65];
        {
            const int kr = tid >> 4, d4 = (tid & 15) * 4;
#pragma unroll
            for (int r = 0; r < 4; ++r) {
                const int k = kr + r * 16;
                float4 v = *(const float4*)&W[((size_t)h * FIN + kt * 64 + k) * DD + d4];
                tile[k][d4 + 0] = v.x; tile[k][d4 + 1] = v.y;
                tile[k][d4 + 2] = v.z; tile[k][d4 + 3] = v.w;
            }
        }
        __syncthreads();
        const int d = tid >> 2, kb = (tid & 3) * 16;
        uint16_t tmp[16];
#pragma unroll
        for (int i = 0; i < 16; ++i) tmp[i] = f2bf(tile[kb + i][d]);
        uint4 o0, o1;
        o0.x = tmp[0] | ((uint32_t)tmp[1] << 16);  o0.y = tmp[2] | ((uint32_t)tmp[3] << 16);
        o0.z = tmp[4] | ((uint32_t)tmp[5] << 16);  o0.w = tmp[6] | ((uint32_t)tmp[7] << 16);
        o1.x = tmp[8] | ((uint32_t)tmp[9] << 16);  o1.y = tmp[10] | ((uint32_t)tmp[11] << 16);
        o1.z = tmp[12] | ((uint32_t)tmp[13] << 16); o1.w = tmp[14] | ((uint32_t)tmp[15] << 16);
        uint16_t* dst = Wt + ((size_t)h * DD + d) * FIN + kt * 64 + kb;
        *(uint4*)dst = o0;
        *(uint4*)(dst + 8) = o1;
        return;
    }
    // ---- build_bits ----
    const int totalWords = KHOP * NN * (NN / 64);  // 524288
    __shared__ int sflag;
    if (tid == 0) sflag = 1;
    __syncthreads();
    bool ok = true;
    for (int i = tid; i < 4096; i += 256) {
        uint32_t w = mraw[i];
        if (!(w == 0u || w == 1u || w == 0x3F800000u)) ok = false;
    }
    if (!ok) sflag = 0;  // benign race: all writers write 0
    __syncthreads();
    const int flag = sflag;

    const int wave_id = (blockIdx.x * 256 + tid) >> 6;  // 4096 waves
    const int lane = tid & 63;

    if (!flag) {  // 1-byte bool elements (observed case)
        const uint8_t* m8 = (const uint8_t*)mraw;
        const uint8_t* base = m8 + (size_t)wave_id * 8192 + (size_t)lane * 16;
        uint4 v[8];
#pragma unroll
        for (int i = 0; i < 8; ++i)
            v[i] = *(const uint4*)(base + (size_t)i * 1024);
        const int idx = (lane & 15) * 4;
#pragma unroll
        for (int i = 0; i < 8; ++i) {
            uint32_t m16 = nz_nib(v[i].x) | (nz_nib(v[i].y) << 4) |
                           (nz_nib(v[i].z) << 8) | (nz_nib(v[i].w) << 12);
            uint32_t u0 = (uint32_t)__shfl((int)m16, idx);
            uint32_t u1 = (uint32_t)__shfl((int)m16, idx + 1);
            uint32_t u2 = (uint32_t)__shfl((int)m16, idx + 2);
            uint32_t u3 = (uint32_t)__shfl((int)m16, idx + 3);
            if (lane < 16) {
                uint64_t wrd = (uint64_t)((u0 & 0xFFFFu) | (u1 << 16)) |
                               ((uint64_t)((u2 & 0xFFFFu) | (u3 << 16)) << 32);
                bits[(size_t)wave_id * 128 + i * 16 + lane] = wrd;
            }
        }
    } else {  // 4-byte elements: ballot path
        const int w0b = wave_id * 128;
        for (int w0 = w0b; w0 < w0b + 128 && w0 < totalWords; w0 += 8) {
            uint32_t v[8];
#pragma unroll
            for (int i = 0; i < 8; ++i)
                v[i] = mraw[(size_t)(w0 + i) * 64 + lane];
#pragma unroll
            for (int i = 0; i < 8; ++i) {
                unsigned long long b = __ballot(v[i] != 0u);
                if (lane == 0) bits[w0 + i] = b;
            }
        }
    }
}

// ---------------- layer-1 GEMM via MFMA: Wh = xb @ W[h], bf16 in/out, fused f1/f2 ----------------
__global__ __launch_bounds__(256) void wh_gemm(const uint16_t* __restrict__ xb,
                                               const uint16_t* __restrict__ Wt,
                                               const float* __restrict__ a1,
                                               const float* __restrict__ a2,
                                               uint16_t* __restrict__ Whb,
                                               float* __restrict__ f1,
                                               float* __restrict__ f2) {
    const int h = blockIdx.y;
    const int n0 = blockIdx.x * 64;
    const int tid = threadIdx.x;
    const int wave = tid >> 6, lane = tid & 63;
    const int q = lane >> 4, r = lane & 15;
    __shared__ uint16_t xs[64 * 72];
    __shared__ uint16_t ws[64 * 72];
    floatx4 acc[4] = {floatx4{0,0,0,0}, floatx4{0,0,0,0}, floatx4{0,0,0,0}, floatx4{0,0,0,0}};

    const int srow = tid >> 2, c16 = (tid & 3) * 16;
    for (int chunk = 0; chunk < 8; ++chunk) {
        const int fc = chunk * 64;
        {   // pure bf16 copy staging (no conversion)
            const uint16_t* xsrc = xb + (size_t)(n0 + srow) * FIN + fc + c16;
            *(uint4*)&xs[srow * 72 + c16]     = *(const uint4*)xsrc;
            *(uint4*)&xs[srow * 72 + c16 + 8] = *(const uint4*)(xsrc + 8);
            const uint16_t* wsrc = Wt + ((size_t)h * DD + srow) * FIN + fc + c16;
            *(uint4*)&ws[srow * 72 + c16]     = *(const uint4*)wsrc;
            *(uint4*)&ws[srow * 72 + c16 + 8] = *(const uint4*)(wsrc + 8);
        }
        __syncthreads();
        const int mrow = wave * 16 + r;
        short8 a0 = *(const short8*)&xs[mrow * 72 + q * 8];
        short8 a1f = *(const short8*)&xs[mrow * 72 + 32 + q * 8];
#pragma unroll
        for (int t = 0; t < 4; ++t) {
            short8 b0 = *(const short8*)&ws[(t * 16 + r) * 72 + q * 8];
            short8 b1 = *(const short8*)&ws[(t * 16 + r) * 72 + 32 + q * 8];
            acc[t] = __builtin_amdgcn_mfma_f32_16x16x32_bf16(a0, b0, acc[t], 0, 0, 0);
            acc[t] = __builtin_amdgcn_mfma_f32_16x16x32_bf16(a1f, b1, acc[t], 0, 0, 0);
        }
        __syncthreads();
    }

#pragma unroll
    for (int t = 0; t < 4; ++t) {
#pragma unroll
        for (int reg = 0; reg < 4; ++reg) {
            const int m = wave * 16 + q * 4 + reg;
            const int d = t * 16 + r;
            Whb[((size_t)h * NN + n0 + m) * DD + d] = f2bf(acc[t][reg]);
        }
    }
    float a1r[4], a2r[4];
#pragma unroll
    for (int t = 0; t < 4; ++t) {
        a1r[t] = a1[h * DD + t * 16 + r];
        a2r[t] = a2[h * DD + t * 16 + r];
    }
#pragma unroll
    for (int reg = 0; reg < 4; ++reg) {
        float p1 = 0.f, p2 = 0.f;
#pragma unroll
        for (int t = 0; t < 4; ++t) {
            p1 += acc[t][reg] * a1r[t];
            p2 += acc[t][reg] * a2r[t];
        }
#pragma unroll
        for (int off = 1; off < 16; off <<= 1) {
            p1 += __shfl_xor(p1, off);
            p2 += __shfl_xor(p2, off);
        }
        if (r == 0) {
            const int m = wave * 16 + q * 4 + reg;
            f1[h * NN + n0 + m] = p1;
            f2[h * NN + n0 + m] = p2;
        }
    }
}

// ---------------- layer-1 attention (dwordx4 gather: 8 nbrs/step) + fused output GEMM ----------
__global__ __launch_bounds__(512) void attn1(const uint64_t* __restrict__ bits,
                                             const uint16_t* __restrict__ Whb,
                                             const float* __restrict__ f1,
                                             const float* __restrict__ f2,
                                             const float* __restrict__ Wout,
                                             const float* __restrict__ ao1,
                                             const float* __restrict__ ao2,
                                             float* __restrict__ Who,
                                             float* __restrict__ g1,
                                             float* __restrict__ g2) {
    const int n = blockIdx.x;
    const int tid = threadIdx.x;
    const int h = tid >> 6, lane = tid & 63;
    const int ng = lane >> 3;                 // neighbor slot 0..7
    const int dl = lane & 7;                  // dim-group 0..7 (8 dims each)
    const uint32_t dby = (uint32_t)dl * 16;   // 16 B = 8 bf16 dims
    __shared__ uint16_t nbr[KHOP][NN];
    __shared__ uint2 wm[HH][64];
    __shared__ float xrow[HH * DD];
    __shared__ float part[32][17];
    __shared__ int cnt[KHOP];
    if (h < KHOP) {
        const int hop = h;
        if (lane == 0) cnt[hop] = 0;
        uint64_t v = bits[((size_t)hop * NN + n) * 64 + lane];
        int c = __popcll(v);
        int base = 0;
        if (c) base = atomicAdd(&cnt[hop], c);
        int mb = lane * 64;
        while (v) {
            int j = __ffsll((unsigned long long)v) - 1;
            nbr[hop][base++] = (uint16_t)(mb + j);
            v &= v - 1;
        }
    }
    const float f1n = f1[h * NN + n];
    const float* __restrict__ f2h = f2 + h * NN;
    const uint16_t* __restrict__ hb = Whb + (size_t)h * NN * DD;  // wave-uniform base
    __syncthreads();
    float res[8] = {0.f,0.f,0.f,0.f,0.f,0.f,0.f,0.f};
    for (int hop = 0; hop < KHOP; ++hop) {
        const int count = cnt[hop];
        const uint16_t* __restrict__ nb = nbr[hop];
        uint2* __restrict__ wmh = wm[h];
        float acc[8] = {0.f,0.f,0.f,0.f,0.f,0.f,0.f,0.f};
        float denp = 0.f;
        for (int b0 = 0; b0 < count; b0 += 64) {
            const int bs = min(64, count - b0);
            uint32_t wbits = 0u, moff = 0u;
            if (lane < bs) {
                int m = nb[b0 + lane];
                float e = f1n + f2h[m];
                e = (e > 0.f) ? e : ALPHA * e;
                float w = __expf(e);
                denp += w;
                wbits = __float_as_uint(w);
                moff = (uint32_t)m << 7;  // 128 B / row
            }
            wmh[lane] = make_uint2(wbits, moff);  // same-wave LDS: ordered, no barrier
            const int ngrp = (bs + 15) >> 4;      // 16 neighbors / group (2 steps batched)
            for (int g = 0; g < ngrp; ++g) {
                const uint2 p0 = wmh[g * 16 + ng];
                const uint2 p1 = wmh[g * 16 + 8 + ng];
                const uint4 d0 = *(const uint4*)((const char*)hb + (p0.y + dby));
                const uint4 d1 = *(const uint4*)((const char*)hb + (p1.y + dby));
                const float w0 = __uint_as_float(p0.x);
                const float w1 = __uint_as_float(p1.x);
                acc[0] += w0 * __uint_as_float(d0.x << 16);
                acc[1] += w0 * __uint_as_float(d0.x & 0xFFFF0000u);
                acc[2] += w0 * __uint_as_float(d0.y << 16);
                acc[3] += w0 * __uint_as_float(d0.y & 0xFFFF0000u);
                acc[4] += w0 * __uint_as_float(d0.z << 16);
                acc[5] += w0 * __uint_as_float(d0.z & 0xFFFF0000u);
                acc[6] += w0 * __uint_as_float(d0.w << 16);
                acc[7] += w0 * __uint_as_float(d0.w & 0xFFFF0000u);
                acc[0] += w1 * __uint_as_float(d1.x << 16);
                acc[1] += w1 * __uint_as_float(d1.x & 0xFFFF0000u);
                acc[2] += w1 * __uint_as_float(d1.y << 16);
                acc[3] += w1 * __uint_as_float(d1.y & 0xFFFF0000u);
                acc[4] += w1 * __uint_as_float(d1.z << 16);
                acc[5] += w1 * __uint_as_float(d1.z & 0xFFFF0000u);
                acc[6] += w1 * __uint_as_float(d1.w << 16);
                acc[7] += w1 * __uint_as_float(d1.w & 0xFFFF0000u);
            }
        }
        float den = denp;
#pragma unroll
        for (int off = 1; off < 64; off <<= 1) den += __shfl_xor(den, off);
#pragma unroll
        for (int off = 8; off < 64; off <<= 1) {
#pragma unroll
            for (int d = 0; d < 8; ++d) acc[d] += __shfl_xor(acc[d], off);
        }
        const float scale = ((hop == 0) ? 1.f : BETA) / den;
#pragma unroll
        for (int d = 0; d < 8; ++d) res[d] += scale * acc[d];
    }
    if (ng == 0) {  // lanes 0..7: dl == lane
#pragma unroll
        for (int d = 0; d < 8; ++d) {
            const float v = res[d];
            xrow[h * DD + dl * 8 + d] = (v > 0.f) ? v : (__expf(v) - 1.f);
        }
    }
    __syncthreads();
    {
        const int c = tid & 15, chunk = tid >> 4;
        float p = 0.f;
#pragma unroll
        for (int i = 0; i < 16; ++i)
            p += xrow[chunk * 16 + i] * Wout[(chunk * 16 + i) * CC + c];
        part[chunk][c] = p;
    }
    __syncthreads();
    if (tid < 16) {
        float s = 0.f;
#pragma unroll
        for (int k = 0; k < 32; ++k) s += part[k][tid];
        Who[n * CC + tid] = s;
        float p1 = s * ao1[tid];
        float p2 = s * ao2[tid];
#pragma unroll
        for (int off = 1; off < 16; off <<= 1) {
            p1 += __shfl_xor(p1, off);
            p2 += __shfl_xor(p2, off);
        }
        if (tid == 0) { g1[n] = p1; g2[n] = p2; }
    }
}

// ---------------- layer-2 attention (float4 gather: 16 nbrs/step) + elu + log_softmax ----------
__global__ __launch_bounds__(256) void attn2(const uint64_t* __restrict__ bits,
                                             const float* __restrict__ Who,
                                             const float* __restrict__ g1,
                                             const float* __restrict__ g2,
                                             float* __restrict__ out) {
    const int wv = threadIdx.x >> 6;
    const int lane = threadIdx.x & 63;
    const int n = blockIdx.x * 4 + wv;
    __shared__ uint16_t nbr[4][NN];
    uint16_t* mynbr = nbr[wv];
    const float g1n = g1[n];
    const int s4 = lane >> 2, cg = lane & 3;  // neighbor slot 0..15, class-group 0..3
    const uint32_t cby = (uint32_t)cg * 16;   // 16 B = 4 f32 classes
    float res[4] = {0.f,0.f,0.f,0.f};
    for (int hop = 0; hop < KHOP; ++hop) {
        uint64_t v = bits[((size_t)hop * NN + n) * 64 + lane];
        int cpc = __popcll(v);
        int pref = cpc;
        for (int off = 1; off < 64; off <<= 1) {
            int t = __shfl_up(pref, off);
            if (lane >= off) pref += t;
        }
        int total = __shfl(pref, 63);
        int base = pref - cpc;
        int mb = lane * 64;
        while (v) {
            int j = __ffsll((unsigned long long)v) - 1;
            mynbr[base++] = (uint16_t)(mb + j);
            v &= v - 1;
        }
        float acc[4] = {0.f,0.f,0.f,0.f};
        float denp = 0.f;
        for (int b0 = 0; b0 < total; b0 += 64) {
            const int bs = min(64, total - b0);
            float w = 0.f; uint32_t moff = 0u;
            if (lane < bs) {
                int m = mynbr[b0 + lane];
                float e = g1n + g2[m];
                e = (e > 0.f) ? e : ALPHA * e;
                w = __expf(e);
                moff = (uint32_t)m << 6;  // fp32 row of 16 floats = 64 B
            }
            denp += w;
            const int nstep = (bs + 15) >> 4;
            for (int i = 0; i < nstep; ++i) {
                const int j = 16 * i + s4;   // j<64 always; pad lanes give w=0/moff=0
                const float wj = __shfl(w, j);
                const uint32_t oj = (uint32_t)__shfl((int)moff, j);
                const float4 vv = *(const float4*)((const char*)Who + (oj + cby));
                acc[0] += wj * vv.x;
                acc[1] += wj * vv.y;
                acc[2] += wj * vv.z;
                acc[3] += wj * vv.w;
            }
        }
        float den = denp;
#pragma unroll
        for (int off = 1; off < 64; off <<= 1) den += __shfl_xor(den, off);
#pragma unroll
        for (int off = 4; off < 64; off <<= 1) {
#pragma unroll
            for (int d = 0; d < 4; ++d) acc[d] += __shfl_xor(acc[d], off);
        }
        const float sc = ((hop == 0) ? 1.f : BETA) / den;
#pragma unroll
        for (int d = 0; d < 4; ++d) res[d] += sc * acc[d];
    }
    float o[4];
#pragma unroll
    for (int d = 0; d < 4; ++d) o[d] = (res[d] > 0.f) ? res[d] : (__expf(res[d]) - 1.f);
    float mx = fmaxf(fmaxf(o[0], o[1]), fmaxf(o[2], o[3]));
#pragma unroll
    for (int off = 1; off < 4; off <<= 1) mx = fmaxf(mx, __shfl_xor(mx, off));
    float s = 0.f;
#pragma unroll
    for (int d = 0; d < 4; ++d) s += __expf(o[d] - mx);
#pragma unroll
    for (int off = 1; off < 4; off <<= 1) s += __shfl_xor(s, off);
    const float lg = __logf(s);
    if (s4 == 0) {  // lanes 0..3 write classes cg*4..cg*4+3
        float4 r;
        r.x = o[0] - mx - lg; r.y = o[1] - mx - lg;
        r.z = o[2] - mx - lg; r.w = o[3] - mx - lg;
        *(float4*)&out[(size_t)n * CC + cg * 4] = r;
    }
}

extern "C" void kernel_launch(void* const* d_in, const int* in_sizes, int n_in,
                              void* d_out, int out_size, void* d_ws, size_t ws_size,
                              hipStream_t stream) {
    const float* x    = (const float*)d_in[0];
    const void*  masks= d_in[1];
    const float* W    = (const float*)d_in[2];
    const float* a1   = (const float*)d_in[3];
    const float* a2   = (const float*)d_in[4];
    const float* Wout = (const float*)d_in[5];
    const float* ao1  = (const float*)d_in[6];
    const float* ao2  = (const float*)d_in[7];
    float* out = (float*)d_out;

    char* ws = (char*)d_ws;
    uint64_t* bits = (uint64_t*)ws;                         // 4 MB
    uint16_t* Whb  = (uint16_t*)(ws + (size_t)KHOP * NN * 64 * 8);  // 4 MB (bf16)
    float* f1  = (float*)(Whb + (size_t)HH * NN * DD);      // 128 KB
    float* f2  = f1 + (size_t)HH * NN;                      // 128 KB
    float* Who = f2 + (size_t)HH * NN;                      // 256 KB
    float* g1  = Who + (size_t)NN * CC;                     // 16 KB
    float* g2  = g1 + NN;                                   // 16 KB
    uint16_t* Wt = (uint16_t*)(g2 + NN);                    // 512 KB (bf16 W^T)
    uint16_t* xb = Wt + (size_t)HH * DD * FIN;              // 4 MB (bf16 x)

    bits_prep<<<1088 + 512, 256, 0, stream>>>((const uint32_t*)masks, bits, W, Wt, x, xb);
    wh_gemm<<<dim3(NN / 64, HH), 256, 0, stream>>>(xb, Wt, a1, a2, Whb, f1, f2);
    attn1<<<NN, 512, 0, stream>>>(bits, Whb, f1, f2, Wout, ao1, ao2, Who, g1, g2);
    attn2<<<NN / 4, 256, 0, stream>>>(bits, Who, g1, g2, out);
    (void)in_sizes; (void)n_in; (void)out_size; (void)ws_size;
}